// Round 5
// baseline (882.618 us; speedup 1.0000x reference)
//
#include <hip/hip_runtime.h>
#include <cstdint>
#include <cstddef>

#define N_TOK 16384
#define E_DIM 512
#define C_DIM 8
#define K_CODES 8192
#define LN_EPS 1e-5f

typedef __attribute__((ext_vector_type(8))) short short8;
typedef __attribute__((ext_vector_type(4))) float f32x4;

// ---------- helpers: fp32 -> bf16 round-nearest-even, hi/lo split ----------
__device__ __forceinline__ unsigned short bf16_rn(float x) {
  unsigned u = __float_as_uint(x);
  unsigned r = u + 0x7FFFu + ((u >> 16) & 1u);
  return (unsigned short)(r >> 16);
}
__device__ __forceinline__ float bf16_f(unsigned short h) {
  return __uint_as_float(((unsigned)h) << 16);
}

__device__ __forceinline__ void gload16(const void* g, void* l) {
  __builtin_amdgcn_global_load_lds(
      (const __attribute__((address_space(1))) void*)g,
      (__attribute__((address_space(3))) void*)l, 16, 0, 0);
}

// ---------- pack bodies (fragment-linear hi/lo bf16) ----------
// A (M x 512 row-major): t = (mf*16 + kt)*64 + l ; entry = A[mf*16+(l&15)][kt*32+(l>>4)*8 + j]
__device__ __forceinline__ void pack_a_body(const float* __restrict__ A,
    unsigned short* __restrict__ hi, unsigned short* __restrict__ lo, int t) {
  int l = t & 63;
  int kt = (t >> 6) & 15;
  int mf = t >> 10;
  const float* src = A + (size_t)(mf * 16 + (l & 15)) * 512 + kt * 32 + (l >> 4) * 8;
  float4 x0 = *(const float4*)src;
  float4 x1 = *(const float4*)(src + 4);
  float xs[8] = {x0.x, x0.y, x0.z, x0.w, x1.x, x1.y, x1.z, x1.w};
  unsigned hw[4], lw[4];
#pragma unroll
  for (int p = 0; p < 4; ++p) {
    float a = xs[2 * p], b = xs[2 * p + 1];
    unsigned short ha = bf16_rn(a), hb = bf16_rn(b);
    unsigned short la = bf16_rn(a - bf16_f(ha)), lb = bf16_rn(b - bf16_f(hb));
    hw[p] = (unsigned)ha | ((unsigned)hb << 16);
    lw[p] = (unsigned)la | ((unsigned)lb << 16);
  }
  uint4 hv; hv.x = hw[0]; hv.y = hw[1]; hv.z = hw[2]; hv.w = hw[3];
  uint4 lv; lv.x = lw[0]; lv.y = lw[1]; lv.z = lw[2]; lv.w = lw[3];
  ((uint4*)hi)[t] = hv;
  ((uint4*)lo)[t] = lv;
}

// B (512 x 512 K x N row-major): t = (nf*16 + kt)*64 + l ; entry = B[kt*32+(l>>4)*8+j][nf*16+(l&15)]
__device__ __forceinline__ void pack_b_body(const float* __restrict__ B,
    unsigned short* __restrict__ hi, unsigned short* __restrict__ lo, int t) {
  int l = t & 63;
  int kt = (t >> 6) & 15;
  int nf = t >> 10;
  int col = nf * 16 + (l & 15);
  int krow = kt * 32 + (l >> 4) * 8;
  unsigned hw[4], lw[4];
#pragma unroll
  for (int p = 0; p < 4; ++p) {
    float a = B[(size_t)(krow + 2 * p) * 512 + col];
    float b = B[(size_t)(krow + 2 * p + 1) * 512 + col];
    unsigned short ha = bf16_rn(a), hb = bf16_rn(b);
    unsigned short la = bf16_rn(a - bf16_f(ha)), lb = bf16_rn(b - bf16_f(hb));
    hw[p] = (unsigned)ha | ((unsigned)hb << 16);
    lw[p] = (unsigned)la | ((unsigned)lb << 16);
  }
  uint4 hv; hv.x = hw[0]; hv.y = hw[1]; hv.z = hw[2]; hv.w = hw[3];
  uint4 lv; lv.x = lw[0]; lv.y = lw[1]; lv.z = lw[2]; lv.w = lw[3];
  ((uint4*)hi)[t] = hv;
  ((uint4*)lo)[t] = lv;
}

// ---------- fused prep: pack A1 | pack B1 | pack B2 | ne | proj_out1 -> packed A2 ----------
__global__ __launch_bounds__(256) void prep(const float* __restrict__ features,
    const float* __restrict__ W1_in, const float* __restrict__ W2_out,
    const float* __restrict__ emb,
    const float* __restrict__ W1_out, const float* __restrict__ b1_out,
    unsigned short* __restrict__ A1h, unsigned short* __restrict__ A1l,
    unsigned short* __restrict__ B1h, unsigned short* __restrict__ B1l,
    unsigned short* __restrict__ B2h, unsigned short* __restrict__ B2l,
    unsigned short* __restrict__ A2h, unsigned short* __restrict__ A2l,
    float* __restrict__ ne) {
  int bid = blockIdx.x;
  int tid = threadIdx.x;
  if (bid < 4096) {
    pack_a_body(features, A1h, A1l, bid * 256 + tid);
  } else if (bid < 4224) {
    pack_b_body(W1_in, B1h, B1l, (bid - 4096) * 256 + tid);
  } else if (bid < 4352) {
    pack_b_body(W2_out, B2h, B2l, (bid - 4224) * 256 + tid);
  } else if (bid < 4384) {
    int k = (bid - 4352) * 256 + tid;
    const float* e = emb + (size_t)k * C_DIM;
    float s = 0.f;
#pragma unroll
    for (int c = 0; c < C_DIM; ++c) s = fmaf(e[c], e[c], s);
    ne[k] = s;
  } else {
    // relu(emb @ W1_out + b1_out) emitted directly in packed hi/lo A-layout
    int mf = bid - 4384;               // 0..511
    int l = tid & 63;
    int kt4 = tid >> 6;                // 0..3
    int k0 = mf * 16 + (l & 15);
    float ev[C_DIM];
#pragma unroll
    for (int c = 0; c < C_DIM; ++c) ev[c] = emb[(size_t)k0 * C_DIM + c];
#pragma unroll
    for (int it = 0; it < 4; ++it) {
      int kt = it * 4 + kt4;
      int e0 = kt * 32 + (l >> 4) * 8;
      float o[8];
      float4 bv0 = *(const float4*)(b1_out + e0);
      float4 bv1 = *(const float4*)(b1_out + e0 + 4);
      o[0] = bv0.x; o[1] = bv0.y; o[2] = bv0.z; o[3] = bv0.w;
      o[4] = bv1.x; o[5] = bv1.y; o[6] = bv1.z; o[7] = bv1.w;
#pragma unroll
      for (int c = 0; c < C_DIM; ++c) {
        float4 w0 = *(const float4*)(W1_out + (size_t)c * E_DIM + e0);
        float4 w1 = *(const float4*)(W1_out + (size_t)c * E_DIM + e0 + 4);
        o[0] = fmaf(ev[c], w0.x, o[0]); o[1] = fmaf(ev[c], w0.y, o[1]);
        o[2] = fmaf(ev[c], w0.z, o[2]); o[3] = fmaf(ev[c], w0.w, o[3]);
        o[4] = fmaf(ev[c], w1.x, o[4]); o[5] = fmaf(ev[c], w1.y, o[5]);
        o[6] = fmaf(ev[c], w1.z, o[6]); o[7] = fmaf(ev[c], w1.w, o[7]);
      }
      unsigned hw[4], lw[4];
#pragma unroll
      for (int p = 0; p < 4; ++p) {
        float a = fmaxf(o[2 * p], 0.f), b = fmaxf(o[2 * p + 1], 0.f);
        unsigned short ha = bf16_rn(a), hb = bf16_rn(b);
        unsigned short la = bf16_rn(a - bf16_f(ha)), lb = bf16_rn(b - bf16_f(hb));
        hw[p] = (unsigned)ha | ((unsigned)hb << 16);
        lw[p] = (unsigned)la | ((unsigned)lb << 16);
      }
      size_t t = ((size_t)mf * 16 + kt) * 64 + l;
      uint4 hv; hv.x = hw[0]; hv.y = hw[1]; hv.z = hw[2]; hv.w = hw[3];
      uint4 lv; lv.x = lw[0]; lv.y = lw[1]; lv.z = lw[2]; lv.w = lw[3];
      ((uint4*)A2h)[t] = hv;
      ((uint4*)A2l)[t] = lv;
    }
  }
}

// ---------- split-bf16 MFMA GEMM, 2-phase pipelined, N=K=512 ----------
// BM=128 BN=128 BK=32, 4 waves (2x2), wave tile 64x64 = 4x4 fragments of 16x16
// acc += Ahi*Bhi + Ahi*Blo + Alo*Bhi in 3 SWEEPS (same-dst MFMAs spaced 16 apart).
// If zb != null, each block also zeroes 32768 float4 of it (8/thread/K-step),
// INTERLEAVED into the K-loop so the stores ride the idle memory pipe.
template<bool RELU>
__global__ __launch_bounds__(256) void gemm_mfma(const unsigned short* __restrict__ Ah,
    const unsigned short* __restrict__ Al, const unsigned short* __restrict__ Bh,
    const unsigned short* __restrict__ Bl, const float* __restrict__ bias,
    float* __restrict__ C, float4* __restrict__ zb) {
  __shared__ char smem[65536];   // 2 buffers x (Ahi 8K | Alo 8K | Bhi 8K | Blo 8K)
  const int tid = threadIdx.x;
  const int l = tid & 63;
  const int w = tid >> 6;
  const int wm = w >> 1, wn = w & 1;
  const int mblk = blockIdx.y, nblk = blockIdx.x;

  const char* gAh = (const char*)Ah + (((size_t)(mblk * 8 + 2 * w) * 16) * 64 + l) * 16;
  const char* gAl = (const char*)Al + (((size_t)(mblk * 8 + 2 * w) * 16) * 64 + l) * 16;
  const char* gBh = (const char*)Bh + (((size_t)(nblk * 8 + 2 * w) * 16) * 64 + l) * 16;
  const char* gBl = (const char*)Bl + (((size_t)(nblk * 8 + 2 * w) * 16) * 64 + l) * 16;

  const size_t zbase = (size_t)(blockIdx.y * gridDim.x + blockIdx.x) * 32768 + tid;

  f32x4 acc[4][4];
#pragma unroll
  for (int i = 0; i < 4; ++i)
#pragma unroll
    for (int j = 0; j < 4; ++j) acc[i][j] = (f32x4){0.f, 0.f, 0.f, 0.f};

  auto stage = [&](int buf, int kt) {
    char* base = smem + buf * 32768;
    const size_t ko = (size_t)kt * 1024;
    char* dA0 = base + (2 * w) * 1024;            // wave-uniform LDS dests
    char* dA1 = base + 8192 + (2 * w) * 1024;
    char* dB0 = base + 16384 + (2 * w) * 1024;
    char* dB1 = base + 24576 + (2 * w) * 1024;
    gload16(gAh + ko,         dA0);
    gload16(gAh + ko + 16384, dA0 + 1024);
    gload16(gAl + ko,         dA1);
    gload16(gAl + ko + 16384, dA1 + 1024);
    gload16(gBh + ko,         dB0);
    gload16(gBh + ko + 16384, dB0 + 1024);
    gload16(gBl + ko,         dB1);
    gload16(gBl + ko + 16384, dB1 + 1024);
  };

  auto zchunk = [&](int c) {                      // 8 coalesced float4 zero-stores
    if (zb) {
      float4 zv = {0.f, 0.f, 0.f, 0.f};
      float4* dst = zb + zbase + (size_t)c * 2048;
#pragma unroll
      for (int u = 0; u < 8; ++u) dst[u * 256] = zv;
    }
  };

  auto compute = [&](int buf) {
    const char* base = smem + buf * 32768;
    const short8* sAh = (const short8*)(base);
    const short8* sAl = (const short8*)(base + 8192);
    const short8* sBh = (const short8*)(base + 16384);
    const short8* sBl = (const short8*)(base + 24576);
    short8 a_h[4], a_l[4], b_h[4], b_l[4];
#pragma unroll
    for (int i = 0; i < 4; ++i) {
      a_h[i] = sAh[(wm * 4 + i) * 64 + l];
      a_l[i] = sAl[(wm * 4 + i) * 64 + l];
    }
#pragma unroll
    for (int j = 0; j < 4; ++j) {
      b_h[j] = sBh[(wn * 4 + j) * 64 + l];
      b_l[j] = sBl[(wn * 4 + j) * 64 + l];
    }
    // sweep 1: hi*hi for all 16 fragments (no back-to-back same-dst deps)
#pragma unroll
    for (int i = 0; i < 4; ++i)
#pragma unroll
      for (int j = 0; j < 4; ++j)
        acc[i][j] = __builtin_amdgcn_mfma_f32_16x16x32_bf16(a_h[i], b_h[j], acc[i][j], 0, 0, 0);
    // sweep 2: hi*lo
#pragma unroll
    for (int i = 0; i < 4; ++i)
#pragma unroll
      for (int j = 0; j < 4; ++j)
        acc[i][j] = __builtin_amdgcn_mfma_f32_16x16x32_bf16(a_h[i], b_l[j], acc[i][j], 0, 0, 0);
    // sweep 3: lo*hi
#pragma unroll
    for (int i = 0; i < 4; ++i)
#pragma unroll
      for (int j = 0; j < 4; ++j)
        acc[i][j] = __builtin_amdgcn_mfma_f32_16x16x32_bf16(a_l[i], b_h[j], acc[i][j], 0, 0, 0);
  };

  stage(0, 0);
  zchunk(0);
  __syncthreads();
  int cur = 0;
#pragma unroll 1
  for (int kt = 1; kt < 16; ++kt) {
    stage(cur ^ 1, kt);
    zchunk(kt);
    compute(cur);
    __syncthreads();
    cur ^= 1;
  }
  compute(cur);

  // epilogue: D col = lane&15, row = (lane>>4)*4 + r
  const int colb = nblk * 128 + wn * 64 + (l & 15);
  const int rowb = mblk * 128 + wm * 64 + ((l >> 4) << 2);
#pragma unroll
  for (int j = 0; j < 4; ++j) {
    float bv = bias[colb + j * 16];
#pragma unroll
    for (int i = 0; i < 4; ++i) {
#pragma unroll
      for (int r = 0; r < 4; ++r) {
        float v = acc[i][j][r] + bv;
        if (RELU) v = fmaxf(v, 0.f);
        C[(size_t)(rowb + i * 16 + r) * 512 + colb + j * 16] = v;
      }
    }
  }
}

// ---------- z = LN(h @ W2_in + b2) over C=8; one wave per token ----------
__global__ __launch_bounds__(256) void zln_kernel(const float* __restrict__ h,
    const float* __restrict__ W2, const float* __restrict__ b2,
    const float* __restrict__ g, const float* __restrict__ b,
    float* __restrict__ z) {
  int token = blockIdx.x * 4 + (threadIdx.x >> 6);
  int lane = threadIdx.x & 63;
  const float* hr = h + (size_t)token * E_DIM;
  float acc[C_DIM];
#pragma unroll
  for (int c = 0; c < C_DIM; ++c) acc[c] = 0.f;
  for (int e = lane; e < E_DIM; e += 64) {
    float hv = hr[e];
    const float* w = W2 + e * C_DIM;
#pragma unroll
    for (int c = 0; c < C_DIM; ++c) acc[c] = fmaf(hv, w[c], acc[c]);
  }
#pragma unroll
  for (int c = 0; c < C_DIM; ++c) {
#pragma unroll
    for (int off = 32; off > 0; off >>= 1) acc[c] += __shfl_down(acc[c], off);
  }
  if (lane == 0) {
    float v[C_DIM]; float mu = 0.f;
#pragma unroll
    for (int c = 0; c < C_DIM; ++c) { v[c] = acc[c] + b2[c]; mu += v[c]; }
    mu *= 0.125f;
    float var = 0.f;
#pragma unroll
    for (int c = 0; c < C_DIM; ++c) { float d = v[c] - mu; var += d * d; }
    var *= 0.125f;
    float inv = 1.0f / sqrtf(var + LN_EPS);
#pragma unroll
    for (int c = 0; c < C_DIM; ++c)
      z[(size_t)token * C_DIM + c] = ((v[c] - mu) * inv) * g[c] + b[c];
  }
}

// ---------- partial argmin; optionally zeroes 16384 float4 of zb, interleaved ----------
__global__ __launch_bounds__(256) void vq_partial(const float* __restrict__ z,
    const float* __restrict__ emb, const float* __restrict__ ne,
    float* __restrict__ pbest, int* __restrict__ pidx, float4* __restrict__ zb) {
  int chunk = blockIdx.x & 7;                 // 8 chunks of 1024 codes
  int token = (blockIdx.x >> 3) * 256 + threadIdx.x;
  float zv[C_DIM];
#pragma unroll
  for (int c = 0; c < C_DIM; ++c) zv[c] = z[(size_t)token * C_DIM + c];
  float s = 0.f;
#pragma unroll
  for (int c = 0; c < C_DIM; ++c) s = fmaf(zv[c], zv[c], s);
  float best = 3.402823466e38f; int bi = 0;
  int j0 = chunk * 1024;
  const size_t zbase = (size_t)blockIdx.x * 16384 + threadIdx.x;
  float4 z4 = {0.f, 0.f, 0.f, 0.f};
#pragma unroll 1
  for (int jo = 0; jo < 64; ++jo) {
    if (zb) zb[zbase + (size_t)jo * 256] = z4;  // 1 coalesced zero-store / 16 codes
#pragma unroll
    for (int ji = 0; ji < 16; ++ji) {
      int j = j0 + jo * 16 + ji;
      const float* e = emb + (size_t)j * C_DIM;  // uniform address -> s_load
      float p = 0.f;
#pragma unroll
      for (int c = 0; c < C_DIM; ++c) p = fmaf(zv[c], e[c], p);
      float d = fmaf(-2.f, p, s) + ne[j];
      if (d < best) { best = d; bi = j; }        // strict < : first-occurrence argmin
    }
  }
  pbest[chunk * N_TOK + token] = best;
  pidx[chunk * N_TOK + token] = bi;
}

// ---------- fused combine + gather + LayerNorm (+ one-hot plant) ----------
__global__ __launch_bounds__(128) void gather_ln(const float* __restrict__ oc,
    const float* __restrict__ pbest, const int* __restrict__ pidx,
    const float* __restrict__ gw, const float* __restrict__ bw,
    float* __restrict__ q, float* __restrict__ idxf, float* __restrict__ enc_plant) {
  int n = blockIdx.x;
  int tid = threadIdx.x;
  // combine 8 chunk-partials (uniform scalar loads; ascending chunk keeps first-occ.)
  float best = pbest[n]; int k = pidx[n];
#pragma unroll
  for (int c = 1; c < 8; ++c) {
    float bb = pbest[c * N_TOK + n]; int i2 = pidx[c * N_TOK + n];
    if (bb < best) { best = bb; k = i2; }
  }
  const float* r = oc + (size_t)k * E_DIM;
  float4 v = ((const float4*)r)[tid];
  __shared__ float red[4];
  int lane = tid & 63, wid = tid >> 6;
  float sum = v.x + v.y + v.z + v.w;
#pragma unroll
  for (int off = 32; off > 0; off >>= 1) sum += __shfl_xor(sum, off);
  if (lane == 0) red[wid] = sum;
  __syncthreads();
  float mu = (red[0] + red[1]) * (1.0f / 512.0f);
  float4 d;
  d.x = v.x - mu; d.y = v.y - mu; d.z = v.z - mu; d.w = v.w - mu;
  float sq = d.x * d.x + d.y * d.y + d.z * d.z + d.w * d.w;
#pragma unroll
  for (int off = 32; off > 0; off >>= 1) sq += __shfl_xor(sq, off);
  if (lane == 0) red[2 + wid] = sq;
  __syncthreads();
  float var = (red[2] + red[3]) * (1.0f / 512.0f);
  float inv = 1.0f / sqrtf(var + LN_EPS);
  float4 gg = ((const float4*)gw)[tid];
  float4 bb = ((const float4*)bw)[tid];
  float4 o;
  o.x = d.x * inv * gg.x + bb.x;
  o.y = d.y * inv * gg.y + bb.y;
  o.z = d.z * inv * gg.z + bb.z;
  o.w = d.w * inv * gg.w + bb.w;
  ((float4*)(q + (size_t)n * E_DIM))[tid] = o;
  if (tid == 0) {
    idxf[n] = (float)k;
    if (enc_plant) enc_plant[(size_t)n * K_CODES + k] = 1.0f;  // enc already zeroed
  }
}

// ---------- FALLBACK ONLY: zero the encodings row and plant the 1.0, coalesced ----------
__global__ __launch_bounds__(256) void zero_scatter(const float* __restrict__ idxf,
    float* __restrict__ enc) {
  int n = blockIdx.x;
  int tid = threadIdx.x;
  int k = (int)idxf[n];                         // idxf lives OUTSIDE enc region
  float* row = enc + (size_t)n * K_CODES;       // 8192 floats = 2048 float4
  float4 zv = {0.f, 0.f, 0.f, 0.f};
#pragma unroll
  for (int u = 0; u < 8; ++u)
    ((float4*)row)[u * 256 + tid] = zv;
  if (((k >> 2) & 255) == tid) row[k] = 1.0f;   // same-thread ordered overwrite
}

extern "C" void kernel_launch(void* const* d_in, const int* in_sizes, int n_in,
                              void* d_out, int out_size, void* d_ws, size_t ws_size,
                              hipStream_t stream) {
  const float* features = (const float*)d_in[0];
  const float* W1_in  = (const float*)d_in[1];
  const float* b1_in  = (const float*)d_in[2];
  const float* W2_in  = (const float*)d_in[3];
  const float* b2_in  = (const float*)d_in[4];
  const float* ln_in_g = (const float*)d_in[5];
  const float* ln_in_b = (const float*)d_in[6];
  const float* emb    = (const float*)d_in[7];
  const float* W1_out = (const float*)d_in[8];
  const float* b1_out = (const float*)d_in[9];
  const float* W2_out = (const float*)d_in[10];
  const float* b2_out = (const float*)d_in[11];
  const float* ln_out_g = (const float*)d_in[12];
  const float* ln_out_b = (const float*)d_in[13];

  float* q    = (float*)d_out;                       // N*E
  float* idxf = q + (size_t)N_TOK * E_DIM;           // N (as float)
  float* enc  = idxf + N_TOK;                        // N*K one-hot

  // Main path: scratch in d_ws; enc zeroed inside gemm1/gemm2/vq (hidden writes).
  // Fallback (small ws): scratch inside enc + trailing zero_scatter (round-4 path).
  const size_t WS_NEED = 26091520ULL * 4ULL;   // 104.4 MB
  const bool use_ws = (d_ws != nullptr) && (ws_size >= WS_NEED);

  float *h, *g, *z, *ne, *pbest; int* pidx;
  unsigned short *A1h, *A1l, *A2h, *A2l, *B1h, *B1l, *B2h, *B2l;
  if (use_ws) {
    float* ws = (float*)d_ws;
    h     = ws;                                // 16384*512
    g     = ws + 8388608;                      // 8192*512
    z     = ws + 12582912;                     // 16384*8
    ne    = ws + 12713984;                     // 8192
    pbest = ws + 12722176;                     // 8*16384
    pidx  = (int*)(ws + 12853248);             // 8*16384
    A1h = (unsigned short*)(ws + 12984320);    // 16384*512 bf16
    A1l = (unsigned short*)(ws + 17178624);
    A2h = (unsigned short*)(ws + 21372928);    // 8192*512 bf16
    A2l = (unsigned short*)(ws + 23470080);
    B1h = (unsigned short*)(ws + 25567232);    // 512*512 bf16
    B1l = (unsigned short*)(ws + 25698304);
    B2h = (unsigned short*)(ws + 25829376);
    B2l = (unsigned short*)(ws + 25960448);    // ends at 26091520
  } else {
    h     = enc;
    g     = enc + 12582912;
    z     = enc + 16777216;
    ne    = enc + 16908288;
    pbest = enc + 16916480;
    pidx  = (int*)(enc + 17063936);
    A1h = (unsigned short*)(enc + 17195008);
    A1l = (unsigned short*)(enc + 21389312);
    A2h = (unsigned short*)(enc + 25583616);
    A2l = (unsigned short*)(enc + 27680768);
    B1h = (unsigned short*)(enc + 29777920);
    B1l = (unsigned short*)(enc + 29908992);
    B2h = (unsigned short*)(enc + 30040064);
    B2l = (unsigned short*)(enc + 30171136);
  }

  // enc zero partition (float4 units): gemm1 [0,16Mi) | gemm2 [16Mi,24Mi) | vq [24Mi,32Mi)
  float4* encv = (float4*)enc;
  float4* zb1 = use_ws ? encv            : nullptr;  // 512 blk * 32768
  float4* zb2 = use_ws ? encv + 16777216 : nullptr;  // 256 blk * 32768
  float4* zbv = use_ws ? encv + 25165824 : nullptr;  // 512 blk * 16384
  float*  plant = use_ws ? enc : nullptr;

  // 1. fused prep (all input-only work)
  prep<<<4896, 256, 0, stream>>>(features, W1_in, W2_out, emb, W1_out, b1_out,
                                 A1h, A1l, B1h, B1l, B2h, B2l, A2h, A2l, ne);

  // 2. project_in: h = relu(features @ W1_in + b1)   [+ zero 256 MB of enc]
  dim3 g1(4, N_TOK / 128);
  gemm_mfma<true><<<g1, 256, 0, stream>>>(A1h, A1l, B1h, B1l, b1_in, h, zb1);

  // 3. z = LN(h @ W2_in + b2)
  zln_kernel<<<N_TOK / 4, 256, 0, stream>>>(h, W2_in, b2_in, ln_in_g, ln_in_b, z);

  // 4. VQ partial argmin                              [+ zero 128 MB of enc]
  vq_partial<<<(N_TOK / 256) * 8, 256, 0, stream>>>(z, emb, ne, pbest, pidx, zbv);

  // 5. project_out GEMM over codebook                 [+ zero 128 MB of enc]
  dim3 g2(4, K_CODES / 128);
  gemm_mfma<false><<<g2, 256, 0, stream>>>(A2h, A2l, B2h, B2l, b2_out, g, zb2);

  // 6. combine + q[n] = LN(g[idx[n]]) + idxf + one-hot plant
  gather_ln<<<N_TOK, 128, 0, stream>>>(g, pbest, pidx, ln_out_g, ln_out_b,
                                       q, idxf, plant);

  // Fallback: scratch lived in enc -> zero+scatter at the end (round-4 behavior)
  if (!use_ws) {
    zero_scatter<<<N_TOK, 256, 0, stream>>>(idxf, enc);
  }
}

// Round 6
// 831.355 us; speedup vs baseline: 1.0617x; 1.0617x over previous
//
#include <hip/hip_runtime.h>
#include <cstdint>
#include <cstddef>

#define N_TOK 16384
#define E_DIM 512
#define C_DIM 8
#define K_CODES 8192
#define LN_EPS 1e-5f

typedef __attribute__((ext_vector_type(8))) short short8;
typedef __attribute__((ext_vector_type(4))) float f32x4;

// ---------- helpers: fp32 -> bf16 round-nearest-even, hi/lo split ----------
__device__ __forceinline__ unsigned short bf16_rn(float x) {
  unsigned u = __float_as_uint(x);
  unsigned r = u + 0x7FFFu + ((u >> 16) & 1u);
  return (unsigned short)(r >> 16);
}
__device__ __forceinline__ float bf16_f(unsigned short h) {
  return __uint_as_float(((unsigned)h) << 16);
}

__device__ __forceinline__ void gload16(const void* g, void* l) {
  __builtin_amdgcn_global_load_lds(
      (const __attribute__((address_space(1))) void*)g,
      (__attribute__((address_space(3))) void*)l, 16, 0, 0);
}

// ---------- pack bodies (fragment-linear hi/lo bf16) ----------
// A (M x 512 row-major): t = (mf*16 + kt)*64 + l ; entry = A[mf*16+(l&15)][kt*32+(l>>4)*8 + j]
__device__ __forceinline__ void pack_a_body(const float* __restrict__ A,
    unsigned short* __restrict__ hi, unsigned short* __restrict__ lo, int t) {
  int l = t & 63;
  int kt = (t >> 6) & 15;
  int mf = t >> 10;
  const float* src = A + (size_t)(mf * 16 + (l & 15)) * 512 + kt * 32 + (l >> 4) * 8;
  float4 x0 = *(const float4*)src;
  float4 x1 = *(const float4*)(src + 4);
  float xs[8] = {x0.x, x0.y, x0.z, x0.w, x1.x, x1.y, x1.z, x1.w};
  unsigned hw[4], lw[4];
#pragma unroll
  for (int p = 0; p < 4; ++p) {
    float a = xs[2 * p], b = xs[2 * p + 1];
    unsigned short ha = bf16_rn(a), hb = bf16_rn(b);
    unsigned short la = bf16_rn(a - bf16_f(ha)), lb = bf16_rn(b - bf16_f(hb));
    hw[p] = (unsigned)ha | ((unsigned)hb << 16);
    lw[p] = (unsigned)la | ((unsigned)lb << 16);
  }
  uint4 hv; hv.x = hw[0]; hv.y = hw[1]; hv.z = hw[2]; hv.w = hw[3];
  uint4 lv; lv.x = lw[0]; lv.y = lw[1]; lv.z = lw[2]; lv.w = lw[3];
  ((uint4*)hi)[t] = hv;
  ((uint4*)lo)[t] = lv;
}

// B (512 x 512 K x N row-major): t = (nf*16 + kt)*64 + l ; entry = B[kt*32+(l>>4)*8+j][nf*16+(l&15)]
__device__ __forceinline__ void pack_b_body(const float* __restrict__ B,
    unsigned short* __restrict__ hi, unsigned short* __restrict__ lo, int t) {
  int l = t & 63;
  int kt = (t >> 6) & 15;
  int nf = t >> 10;
  int col = nf * 16 + (l & 15);
  int krow = kt * 32 + (l >> 4) * 8;
  unsigned hw[4], lw[4];
#pragma unroll
  for (int p = 0; p < 4; ++p) {
    float a = B[(size_t)(krow + 2 * p) * 512 + col];
    float b = B[(size_t)(krow + 2 * p + 1) * 512 + col];
    unsigned short ha = bf16_rn(a), hb = bf16_rn(b);
    unsigned short la = bf16_rn(a - bf16_f(ha)), lb = bf16_rn(b - bf16_f(hb));
    hw[p] = (unsigned)ha | ((unsigned)hb << 16);
    lw[p] = (unsigned)la | ((unsigned)lb << 16);
  }
  uint4 hv; hv.x = hw[0]; hv.y = hw[1]; hv.z = hw[2]; hv.w = hw[3];
  uint4 lv; lv.x = lw[0]; lv.y = lw[1]; lv.z = lw[2]; lv.w = lw[3];
  ((uint4*)hi)[t] = hv;
  ((uint4*)lo)[t] = lv;
}

// ---------- fused prep: pack A1 | pack B1 | pack B2 | ne | proj_out1 -> packed A2 ----------
__global__ __launch_bounds__(256) void prep(const float* __restrict__ features,
    const float* __restrict__ W1_in, const float* __restrict__ W2_out,
    const float* __restrict__ emb,
    const float* __restrict__ W1_out, const float* __restrict__ b1_out,
    unsigned short* __restrict__ A1h, unsigned short* __restrict__ A1l,
    unsigned short* __restrict__ B1h, unsigned short* __restrict__ B1l,
    unsigned short* __restrict__ B2h, unsigned short* __restrict__ B2l,
    unsigned short* __restrict__ A2h, unsigned short* __restrict__ A2l,
    float* __restrict__ ne) {
  int bid = blockIdx.x;
  int tid = threadIdx.x;
  if (bid < 4096) {
    pack_a_body(features, A1h, A1l, bid * 256 + tid);
  } else if (bid < 4224) {
    pack_b_body(W1_in, B1h, B1l, (bid - 4096) * 256 + tid);
  } else if (bid < 4352) {
    pack_b_body(W2_out, B2h, B2l, (bid - 4224) * 256 + tid);
  } else if (bid < 4384) {
    int k = (bid - 4352) * 256 + tid;
    const float* e = emb + (size_t)k * C_DIM;
    float s = 0.f;
#pragma unroll
    for (int c = 0; c < C_DIM; ++c) s = fmaf(e[c], e[c], s);
    ne[k] = s;
  } else {
    // relu(emb @ W1_out + b1_out) emitted directly in packed hi/lo A-layout
    int mf = bid - 4384;               // 0..511
    int l = tid & 63;
    int kt4 = tid >> 6;                // 0..3
    int k0 = mf * 16 + (l & 15);
    float ev[C_DIM];
#pragma unroll
    for (int c = 0; c < C_DIM; ++c) ev[c] = emb[(size_t)k0 * C_DIM + c];
#pragma unroll
    for (int it = 0; it < 4; ++it) {
      int kt = it * 4 + kt4;
      int e0 = kt * 32 + (l >> 4) * 8;
      float o[8];
      float4 bv0 = *(const float4*)(b1_out + e0);
      float4 bv1 = *(const float4*)(b1_out + e0 + 4);
      o[0] = bv0.x; o[1] = bv0.y; o[2] = bv0.z; o[3] = bv0.w;
      o[4] = bv1.x; o[5] = bv1.y; o[6] = bv1.z; o[7] = bv1.w;
#pragma unroll
      for (int c = 0; c < C_DIM; ++c) {
        float4 w0 = *(const float4*)(W1_out + (size_t)c * E_DIM + e0);
        float4 w1 = *(const float4*)(W1_out + (size_t)c * E_DIM + e0 + 4);
        o[0] = fmaf(ev[c], w0.x, o[0]); o[1] = fmaf(ev[c], w0.y, o[1]);
        o[2] = fmaf(ev[c], w0.z, o[2]); o[3] = fmaf(ev[c], w0.w, o[3]);
        o[4] = fmaf(ev[c], w1.x, o[4]); o[5] = fmaf(ev[c], w1.y, o[5]);
        o[6] = fmaf(ev[c], w1.z, o[6]); o[7] = fmaf(ev[c], w1.w, o[7]);
      }
      unsigned hw[4], lw[4];
#pragma unroll
      for (int p = 0; p < 4; ++p) {
        float a = fmaxf(o[2 * p], 0.f), b = fmaxf(o[2 * p + 1], 0.f);
        unsigned short ha = bf16_rn(a), hb = bf16_rn(b);
        unsigned short la = bf16_rn(a - bf16_f(ha)), lb = bf16_rn(b - bf16_f(hb));
        hw[p] = (unsigned)ha | ((unsigned)hb << 16);
        lw[p] = (unsigned)la | ((unsigned)lb << 16);
      }
      size_t t = ((size_t)mf * 16 + kt) * 64 + l;
      uint4 hv; hv.x = hw[0]; hv.y = hw[1]; hv.z = hw[2]; hv.w = hw[3];
      uint4 lv; lv.x = lw[0]; lv.y = lw[1]; lv.z = lw[2]; lv.w = lw[3];
      ((uint4*)A2h)[t] = hv;
      ((uint4*)A2l)[t] = lv;
    }
  }
}

// ---------- split-bf16 MFMA GEMM, 2-phase pipelined, N=K=512 (CLEAN: no extra stores;
// stores would sit behind the per-K-step vmcnt(0) barrier drain — round-5 regression) ----------
template<bool RELU>
__global__ __launch_bounds__(256) void gemm_mfma(const unsigned short* __restrict__ Ah,
    const unsigned short* __restrict__ Al, const unsigned short* __restrict__ Bh,
    const unsigned short* __restrict__ Bl, const float* __restrict__ bias,
    float* __restrict__ C) {
  __shared__ char smem[65536];   // 2 buffers x (Ahi 8K | Alo 8K | Bhi 8K | Blo 8K)
  const int tid = threadIdx.x;
  const int l = tid & 63;
  const int w = tid >> 6;
  const int wm = w >> 1, wn = w & 1;
  const int mblk = blockIdx.y, nblk = blockIdx.x;

  const char* gAh = (const char*)Ah + (((size_t)(mblk * 8 + 2 * w) * 16) * 64 + l) * 16;
  const char* gAl = (const char*)Al + (((size_t)(mblk * 8 + 2 * w) * 16) * 64 + l) * 16;
  const char* gBh = (const char*)Bh + (((size_t)(nblk * 8 + 2 * w) * 16) * 64 + l) * 16;
  const char* gBl = (const char*)Bl + (((size_t)(nblk * 8 + 2 * w) * 16) * 64 + l) * 16;

  f32x4 acc[4][4];
#pragma unroll
  for (int i = 0; i < 4; ++i)
#pragma unroll
    for (int j = 0; j < 4; ++j) acc[i][j] = (f32x4){0.f, 0.f, 0.f, 0.f};

  auto stage = [&](int buf, int kt) {
    char* base = smem + buf * 32768;
    const size_t ko = (size_t)kt * 1024;
    char* dA0 = base + (2 * w) * 1024;            // wave-uniform LDS dests
    char* dA1 = base + 8192 + (2 * w) * 1024;
    char* dB0 = base + 16384 + (2 * w) * 1024;
    char* dB1 = base + 24576 + (2 * w) * 1024;
    gload16(gAh + ko,         dA0);
    gload16(gAh + ko + 16384, dA0 + 1024);
    gload16(gAl + ko,         dA1);
    gload16(gAl + ko + 16384, dA1 + 1024);
    gload16(gBh + ko,         dB0);
    gload16(gBh + ko + 16384, dB0 + 1024);
    gload16(gBl + ko,         dB1);
    gload16(gBl + ko + 16384, dB1 + 1024);
  };

  auto compute = [&](int buf) {
    const char* base = smem + buf * 32768;
    const short8* sAh = (const short8*)(base);
    const short8* sAl = (const short8*)(base + 8192);
    const short8* sBh = (const short8*)(base + 16384);
    const short8* sBl = (const short8*)(base + 24576);
    short8 a_h[4], a_l[4], b_h[4], b_l[4];
#pragma unroll
    for (int i = 0; i < 4; ++i) {
      a_h[i] = sAh[(wm * 4 + i) * 64 + l];
      a_l[i] = sAl[(wm * 4 + i) * 64 + l];
    }
#pragma unroll
    for (int j = 0; j < 4; ++j) {
      b_h[j] = sBh[(wn * 4 + j) * 64 + l];
      b_l[j] = sBl[(wn * 4 + j) * 64 + l];
    }
    // sweep 1: hi*hi for all 16 fragments (no back-to-back same-dst deps)
#pragma unroll
    for (int i = 0; i < 4; ++i)
#pragma unroll
      for (int j = 0; j < 4; ++j)
        acc[i][j] = __builtin_amdgcn_mfma_f32_16x16x32_bf16(a_h[i], b_h[j], acc[i][j], 0, 0, 0);
    // sweep 2: hi*lo
#pragma unroll
    for (int i = 0; i < 4; ++i)
#pragma unroll
      for (int j = 0; j < 4; ++j)
        acc[i][j] = __builtin_amdgcn_mfma_f32_16x16x32_bf16(a_h[i], b_l[j], acc[i][j], 0, 0, 0);
    // sweep 3: lo*hi
#pragma unroll
    for (int i = 0; i < 4; ++i)
#pragma unroll
      for (int j = 0; j < 4; ++j)
        acc[i][j] = __builtin_amdgcn_mfma_f32_16x16x32_bf16(a_l[i], b_h[j], acc[i][j], 0, 0, 0);
  };

  stage(0, 0);
  __syncthreads();
  int cur = 0;
#pragma unroll 1
  for (int kt = 1; kt < 16; ++kt) {
    stage(cur ^ 1, kt);
    compute(cur);
    __syncthreads();
    cur ^= 1;
  }
  compute(cur);

  // epilogue: D col = lane&15, row = (lane>>4)*4 + r
  const int colb = nblk * 128 + wn * 64 + (l & 15);
  const int rowb = mblk * 128 + wm * 64 + ((l >> 4) << 2);
#pragma unroll
  for (int j = 0; j < 4; ++j) {
    float bv = bias[colb + j * 16];
#pragma unroll
    for (int i = 0; i < 4; ++i) {
#pragma unroll
      for (int r = 0; r < 4; ++r) {
        float v = acc[i][j][r] + bv;
        if (RELU) v = fmaxf(v, 0.f);
        C[(size_t)(rowb + i * 16 + r) * 512 + colb + j * 16] = v;
      }
    }
  }
}

// ---------- z = LN(h @ W2_in + b2) over C=8; one wave per token ----------
__global__ __launch_bounds__(256) void zln_kernel(const float* __restrict__ h,
    const float* __restrict__ W2, const float* __restrict__ b2,
    const float* __restrict__ g, const float* __restrict__ b,
    float* __restrict__ z) {
  int token = blockIdx.x * 4 + (threadIdx.x >> 6);
  int lane = threadIdx.x & 63;
  const float* hr = h + (size_t)token * E_DIM;
  float acc[C_DIM];
#pragma unroll
  for (int c = 0; c < C_DIM; ++c) acc[c] = 0.f;
  for (int e = lane; e < E_DIM; e += 64) {
    float hv = hr[e];
    const float* w = W2 + e * C_DIM;
#pragma unroll
    for (int c = 0; c < C_DIM; ++c) acc[c] = fmaf(hv, w[c], acc[c]);
  }
#pragma unroll
  for (int c = 0; c < C_DIM; ++c) {
#pragma unroll
    for (int off = 32; off > 0; off >>= 1) acc[c] += __shfl_down(acc[c], off);
  }
  if (lane == 0) {
    float v[C_DIM]; float mu = 0.f;
#pragma unroll
    for (int c = 0; c < C_DIM; ++c) { v[c] = acc[c] + b2[c]; mu += v[c]; }
    mu *= 0.125f;
    float var = 0.f;
#pragma unroll
    for (int c = 0; c < C_DIM; ++c) { float d = v[c] - mu; var += d * d; }
    var *= 0.125f;
    float inv = 1.0f / sqrtf(var + LN_EPS);
#pragma unroll
    for (int c = 0; c < C_DIM; ++c)
      z[(size_t)token * C_DIM + c] = ((v[c] - mu) * inv) * g[c] + b[c];
  }
}

// ---------- partial argmin + FULL enc zeroing (barrier-free carrier) ----------
// No __syncthreads in this kernel -> zero-stores are fire-and-forget and ride the
// memory pipe under the VALU argmin loop (no vmcnt(0) drain on a barrier path).
// Each of the 512 blocks zeroes a disjoint 65536-float4 (1 MB) range: 256/thread.
__global__ __launch_bounds__(256) void vq_partial(const float* __restrict__ z,
    const float* __restrict__ emb, const float* __restrict__ ne,
    float* __restrict__ pbest, int* __restrict__ pidx, float4* __restrict__ zb) {
  int chunk = blockIdx.x & 7;                 // 8 chunks of 1024 codes
  int token = (blockIdx.x >> 3) * 256 + threadIdx.x;
  float zv[C_DIM];
#pragma unroll
  for (int c = 0; c < C_DIM; ++c) zv[c] = z[(size_t)token * C_DIM + c];
  float s = 0.f;
#pragma unroll
  for (int c = 0; c < C_DIM; ++c) s = fmaf(zv[c], zv[c], s);
  float best = 3.402823466e38f; int bi = 0;
  int j0 = chunk * 1024;
  const size_t zbase = (size_t)blockIdx.x * 65536 + threadIdx.x;
  float4 z4 = {0.f, 0.f, 0.f, 0.f};
#pragma unroll 1
  for (int jo = 0; jo < 64; ++jo) {
    if (zb) {                                  // 4 coalesced zero-stores / 16 codes
#pragma unroll
      for (int su = 0; su < 4; ++su)
        zb[zbase + (size_t)(jo * 4 + su) * 256] = z4;
    }
#pragma unroll
    for (int ji = 0; ji < 16; ++ji) {
      int j = j0 + jo * 16 + ji;
      const float* e = emb + (size_t)j * C_DIM;  // uniform address -> s_load
      float p = 0.f;
#pragma unroll
      for (int c = 0; c < C_DIM; ++c) p = fmaf(zv[c], e[c], p);
      float d = fmaf(-2.f, p, s) + ne[j];
      if (d < best) { best = d; bi = j; }        // strict < : first-occurrence argmin
    }
  }
  pbest[chunk * N_TOK + token] = best;
  pidx[chunk * N_TOK + token] = bi;
}

// ---------- fused combine + gather + LayerNorm (+ one-hot plant) ----------
__global__ __launch_bounds__(128) void gather_ln(const float* __restrict__ oc,
    const float* __restrict__ pbest, const int* __restrict__ pidx,
    const float* __restrict__ gw, const float* __restrict__ bw,
    float* __restrict__ q, float* __restrict__ idxf, float* __restrict__ enc_plant) {
  int n = blockIdx.x;
  int tid = threadIdx.x;
  // combine 8 chunk-partials (uniform scalar loads; ascending chunk keeps first-occ.)
  float best = pbest[n]; int k = pidx[n];
#pragma unroll
  for (int c = 1; c < 8; ++c) {
    float bb = pbest[c * N_TOK + n]; int i2 = pidx[c * N_TOK + n];
    if (bb < best) { best = bb; k = i2; }
  }
  const float* r = oc + (size_t)k * E_DIM;
  float4 v = ((const float4*)r)[tid];
  __shared__ float red[4];
  int lane = tid & 63, wid = tid >> 6;
  float sum = v.x + v.y + v.z + v.w;
#pragma unroll
  for (int off = 32; off > 0; off >>= 1) sum += __shfl_xor(sum, off);
  if (lane == 0) red[wid] = sum;
  __syncthreads();
  float mu = (red[0] + red[1]) * (1.0f / 512.0f);
  float4 d;
  d.x = v.x - mu; d.y = v.y - mu; d.z = v.z - mu; d.w = v.w - mu;
  float sq = d.x * d.x + d.y * d.y + d.z * d.z + d.w * d.w;
#pragma unroll
  for (int off = 32; off > 0; off >>= 1) sq += __shfl_xor(sq, off);
  if (lane == 0) red[2 + wid] = sq;
  __syncthreads();
  float var = (red[2] + red[3]) * (1.0f / 512.0f);
  float inv = 1.0f / sqrtf(var + LN_EPS);
  float4 gg = ((const float4*)gw)[tid];
  float4 bb = ((const float4*)bw)[tid];
  float4 o;
  o.x = d.x * inv * gg.x + bb.x;
  o.y = d.y * inv * gg.y + bb.y;
  o.z = d.z * inv * gg.z + bb.z;
  o.w = d.w * inv * gg.w + bb.w;
  ((float4*)(q + (size_t)n * E_DIM))[tid] = o;
  if (tid == 0) {
    idxf[n] = (float)k;
    if (enc_plant) enc_plant[(size_t)n * K_CODES + k] = 1.0f;  // enc zeroed by vq_partial
  }
}

// ---------- FALLBACK ONLY: zero the encodings row and plant the 1.0, coalesced ----------
__global__ __launch_bounds__(256) void zero_scatter(const float* __restrict__ idxf,
    float* __restrict__ enc) {
  int n = blockIdx.x;
  int tid = threadIdx.x;
  int k = (int)idxf[n];                         // idxf lives OUTSIDE enc region
  float* row = enc + (size_t)n * K_CODES;       // 8192 floats = 2048 float4
  float4 zv = {0.f, 0.f, 0.f, 0.f};
#pragma unroll
  for (int u = 0; u < 8; ++u)
    ((float4*)row)[u * 256 + tid] = zv;
  if (((k >> 2) & 255) == tid) row[k] = 1.0f;   // same-thread ordered overwrite
}

extern "C" void kernel_launch(void* const* d_in, const int* in_sizes, int n_in,
                              void* d_out, int out_size, void* d_ws, size_t ws_size,
                              hipStream_t stream) {
  const float* features = (const float*)d_in[0];
  const float* W1_in  = (const float*)d_in[1];
  const float* b1_in  = (const float*)d_in[2];
  const float* W2_in  = (const float*)d_in[3];
  const float* b2_in  = (const float*)d_in[4];
  const float* ln_in_g = (const float*)d_in[5];
  const float* ln_in_b = (const float*)d_in[6];
  const float* emb    = (const float*)d_in[7];
  const float* W1_out = (const float*)d_in[8];
  const float* b1_out = (const float*)d_in[9];
  const float* W2_out = (const float*)d_in[10];
  const float* b2_out = (const float*)d_in[11];
  const float* ln_out_g = (const float*)d_in[12];
  const float* ln_out_b = (const float*)d_in[13];

  float* q    = (float*)d_out;                       // N*E
  float* idxf = q + (size_t)N_TOK * E_DIM;           // N (as float)
  float* enc  = idxf + N_TOK;                        // N*K one-hot

  // Main path: scratch in d_ws; enc fully zeroed inside vq_partial (barrier-free).
  // Fallback (small ws): scratch inside enc + trailing zero_scatter (round-4 path).
  const size_t WS_NEED = 26091520ULL * 4ULL;   // 104.4 MB
  const bool use_ws = (d_ws != nullptr) && (ws_size >= WS_NEED);

  float *h, *g, *z, *ne, *pbest; int* pidx;
  unsigned short *A1h, *A1l, *A2h, *A2l, *B1h, *B1l, *B2h, *B2l;
  if (use_ws) {
    float* ws = (float*)d_ws;
    h     = ws;                                // 16384*512
    g     = ws + 8388608;                      // 8192*512
    z     = ws + 12582912;                     // 16384*8
    ne    = ws + 12713984;                     // 8192
    pbest = ws + 12722176;                     // 8*16384
    pidx  = (int*)(ws + 12853248);             // 8*16384
    A1h = (unsigned short*)(ws + 12984320);    // 16384*512 bf16
    A1l = (unsigned short*)(ws + 17178624);
    A2h = (unsigned short*)(ws + 21372928);    // 8192*512 bf16
    A2l = (unsigned short*)(ws + 23470080);
    B1h = (unsigned short*)(ws + 25567232);    // 512*512 bf16
    B1l = (unsigned short*)(ws + 25698304);
    B2h = (unsigned short*)(ws + 25829376);
    B2l = (unsigned short*)(ws + 25960448);    // ends at 26091520
  } else {
    h     = enc;
    g     = enc + 12582912;
    z     = enc + 16777216;
    ne    = enc + 16908288;
    pbest = enc + 16916480;
    pidx  = (int*)(enc + 17063936);
    A1h = (unsigned short*)(enc + 17195008);
    A1l = (unsigned short*)(enc + 21389312);
    A2h = (unsigned short*)(enc + 25583616);
    A2l = (unsigned short*)(enc + 27680768);
    B1h = (unsigned short*)(enc + 29777920);
    B1l = (unsigned short*)(enc + 29908992);
    B2h = (unsigned short*)(enc + 30040064);
    B2l = (unsigned short*)(enc + 30171136);
  }

  float4* zbv   = use_ws ? (float4*)enc : nullptr;   // 512 blk * 65536 float4 = 537 MB
  float*  plant = use_ws ? enc : nullptr;

  // 1. fused prep (all input-only work)
  prep<<<4896, 256, 0, stream>>>(features, W1_in, W2_out, emb, W1_out, b1_out,
                                 A1h, A1l, B1h, B1l, B2h, B2l, A2h, A2l, ne);

  // 2. project_in: h = relu(features @ W1_in + b1)
  dim3 g1(4, N_TOK / 128);
  gemm_mfma<true><<<g1, 256, 0, stream>>>(A1h, A1l, B1h, B1l, b1_in, h);

  // 3. z = LN(h @ W2_in + b2)
  zln_kernel<<<N_TOK / 4, 256, 0, stream>>>(h, W2_in, b2_in, ln_in_g, ln_in_b, z);

  // 4. VQ partial argmin  [+ zero ALL 537 MB of enc under the VALU loop]
  vq_partial<<<(N_TOK / 256) * 8, 256, 0, stream>>>(z, emb, ne, pbest, pidx, zbv);

  // 5. project_out GEMM over codebook
  dim3 g2(4, K_CODES / 128);
  gemm_mfma<false><<<g2, 256, 0, stream>>>(A2h, A2l, B2h, B2l, b2_out, g);

  // 6. combine + q[n] = LN(g[idx[n]]) + idxf + one-hot plant (enc zeroed in step 4)
  gather_ln<<<N_TOK, 128, 0, stream>>>(g, pbest, pidx, ln_out_g, ln_out_b,
                                       q, idxf, plant);

  // Fallback: scratch lived in enc -> zero+scatter at the end (round-4 behavior)
  if (!use_ws) {
    zero_scatter<<<N_TOK, 256, 0, stream>>>(idxf, enc);
  }
}

// Round 7
// 786.347 us; speedup vs baseline: 1.1224x; 1.0572x over previous
//
#include <hip/hip_runtime.h>
#include <cstdint>
#include <cstddef>

#define N_TOK 16384
#define E_DIM 512
#define C_DIM 8
#define K_CODES 8192
#define LN_EPS 1e-5f

typedef __attribute__((ext_vector_type(8))) short short8;
typedef __attribute__((ext_vector_type(4))) float f32x4;

// ---------- helpers: fp32 -> bf16 round-nearest-even, hi/lo split ----------
__device__ __forceinline__ unsigned short bf16_rn(float x) {
  unsigned u = __float_as_uint(x);
  unsigned r = u + 0x7FFFu + ((u >> 16) & 1u);
  return (unsigned short)(r >> 16);
}
__device__ __forceinline__ float bf16_f(unsigned short h) {
  return __uint_as_float(((unsigned)h) << 16);
}

__device__ __forceinline__ void gload16(const void* g, void* l) {
  __builtin_amdgcn_global_load_lds(
      (const __attribute__((address_space(1))) void*)g,
      (__attribute__((address_space(3))) void*)l, 16, 0, 0);
}

// ---------- pack bodies (fragment-linear hi/lo bf16) ----------
// A (M x 512 row-major): t = (mf*16 + kt)*64 + l ; entry = A[mf*16+(l&15)][kt*32+(l>>4)*8 + j]
__device__ __forceinline__ void pack_a_body(const float* __restrict__ A,
    unsigned short* __restrict__ hi, unsigned short* __restrict__ lo, int t) {
  int l = t & 63;
  int kt = (t >> 6) & 15;
  int mf = t >> 10;
  const float* src = A + (size_t)(mf * 16 + (l & 15)) * 512 + kt * 32 + (l >> 4) * 8;
  float4 x0 = *(const float4*)src;
  float4 x1 = *(const float4*)(src + 4);
  float xs[8] = {x0.x, x0.y, x0.z, x0.w, x1.x, x1.y, x1.z, x1.w};
  unsigned hw[4], lw[4];
#pragma unroll
  for (int p = 0; p < 4; ++p) {
    float a = xs[2 * p], b = xs[2 * p + 1];
    unsigned short ha = bf16_rn(a), hb = bf16_rn(b);
    unsigned short la = bf16_rn(a - bf16_f(ha)), lb = bf16_rn(b - bf16_f(hb));
    hw[p] = (unsigned)ha | ((unsigned)hb << 16);
    lw[p] = (unsigned)la | ((unsigned)lb << 16);
  }
  uint4 hv; hv.x = hw[0]; hv.y = hw[1]; hv.z = hw[2]; hv.w = hw[3];
  uint4 lv; lv.x = lw[0]; lv.y = lw[1]; lv.z = lw[2]; lv.w = lw[3];
  ((uint4*)hi)[t] = hv;
  ((uint4*)lo)[t] = lv;
}

// B (512 x 512 K x N row-major): t = (nf*16 + kt)*64 + l ; entry = B[kt*32+(l>>4)*8+j][nf*16+(l&15)]
__device__ __forceinline__ void pack_b_body(const float* __restrict__ B,
    unsigned short* __restrict__ hi, unsigned short* __restrict__ lo, int t) {
  int l = t & 63;
  int kt = (t >> 6) & 15;
  int nf = t >> 10;
  int col = nf * 16 + (l & 15);
  int krow = kt * 32 + (l >> 4) * 8;
  unsigned hw[4], lw[4];
#pragma unroll
  for (int p = 0; p < 4; ++p) {
    float a = B[(size_t)(krow + 2 * p) * 512 + col];
    float b = B[(size_t)(krow + 2 * p + 1) * 512 + col];
    unsigned short ha = bf16_rn(a), hb = bf16_rn(b);
    unsigned short la = bf16_rn(a - bf16_f(ha)), lb = bf16_rn(b - bf16_f(hb));
    hw[p] = (unsigned)ha | ((unsigned)hb << 16);
    lw[p] = (unsigned)la | ((unsigned)lb << 16);
  }
  uint4 hv; hv.x = hw[0]; hv.y = hw[1]; hv.z = hw[2]; hv.w = hw[3];
  uint4 lv; lv.x = lw[0]; lv.y = lw[1]; lv.z = lw[2]; lv.w = lw[3];
  ((uint4*)hi)[t] = hv;
  ((uint4*)lo)[t] = lv;
}

// ---------- fused prep: pack A1 | pack B1 | pack B2 | ne | proj_out1 -> packed A2 ----------
__global__ __launch_bounds__(256) void prep(const float* __restrict__ features,
    const float* __restrict__ W1_in, const float* __restrict__ W2_out,
    const float* __restrict__ emb,
    const float* __restrict__ W1_out, const float* __restrict__ b1_out,
    unsigned short* __restrict__ A1h, unsigned short* __restrict__ A1l,
    unsigned short* __restrict__ B1h, unsigned short* __restrict__ B1l,
    unsigned short* __restrict__ B2h, unsigned short* __restrict__ B2l,
    unsigned short* __restrict__ A2h, unsigned short* __restrict__ A2l,
    float* __restrict__ ne) {
  int bid = blockIdx.x;
  int tid = threadIdx.x;
  if (bid < 4096) {
    pack_a_body(features, A1h, A1l, bid * 256 + tid);
  } else if (bid < 4224) {
    pack_b_body(W1_in, B1h, B1l, (bid - 4096) * 256 + tid);
  } else if (bid < 4352) {
    pack_b_body(W2_out, B2h, B2l, (bid - 4224) * 256 + tid);
  } else if (bid < 4384) {
    int k = (bid - 4352) * 256 + tid;
    const float* e = emb + (size_t)k * C_DIM;
    float s = 0.f;
#pragma unroll
    for (int c = 0; c < C_DIM; ++c) s = fmaf(e[c], e[c], s);
    ne[k] = s;
  } else {
    // relu(emb @ W1_out + b1_out) emitted directly in packed hi/lo A-layout
    int mf = bid - 4384;               // 0..511
    int l = tid & 63;
    int kt4 = tid >> 6;                // 0..3
    int k0 = mf * 16 + (l & 15);
    float ev[C_DIM];
#pragma unroll
    for (int c = 0; c < C_DIM; ++c) ev[c] = emb[(size_t)k0 * C_DIM + c];
#pragma unroll
    for (int it = 0; it < 4; ++it) {
      int kt = it * 4 + kt4;
      int e0 = kt * 32 + (l >> 4) * 8;
      float o[8];
      float4 bv0 = *(const float4*)(b1_out + e0);
      float4 bv1 = *(const float4*)(b1_out + e0 + 4);
      o[0] = bv0.x; o[1] = bv0.y; o[2] = bv0.z; o[3] = bv0.w;
      o[4] = bv1.x; o[5] = bv1.y; o[6] = bv1.z; o[7] = bv1.w;
#pragma unroll
      for (int c = 0; c < C_DIM; ++c) {
        float4 w0 = *(const float4*)(W1_out + (size_t)c * E_DIM + e0);
        float4 w1 = *(const float4*)(W1_out + (size_t)c * E_DIM + e0 + 4);
        o[0] = fmaf(ev[c], w0.x, o[0]); o[1] = fmaf(ev[c], w0.y, o[1]);
        o[2] = fmaf(ev[c], w0.z, o[2]); o[3] = fmaf(ev[c], w0.w, o[3]);
        o[4] = fmaf(ev[c], w1.x, o[4]); o[5] = fmaf(ev[c], w1.y, o[5]);
        o[6] = fmaf(ev[c], w1.z, o[6]); o[7] = fmaf(ev[c], w1.w, o[7]);
      }
      unsigned hw[4], lw[4];
#pragma unroll
      for (int p = 0; p < 4; ++p) {
        float a = fmaxf(o[2 * p], 0.f), b = fmaxf(o[2 * p + 1], 0.f);
        unsigned short ha = bf16_rn(a), hb = bf16_rn(b);
        unsigned short la = bf16_rn(a - bf16_f(ha)), lb = bf16_rn(b - bf16_f(hb));
        hw[p] = (unsigned)ha | ((unsigned)hb << 16);
        lw[p] = (unsigned)la | ((unsigned)lb << 16);
      }
      size_t t = ((size_t)mf * 16 + kt) * 64 + l;
      uint4 hv; hv.x = hw[0]; hv.y = hw[1]; hv.z = hw[2]; hv.w = hw[3];
      uint4 lv; lv.x = lw[0]; lv.y = lw[1]; lv.z = lw[2]; lv.w = lw[3];
      ((uint4*)A2h)[t] = hv;
      ((uint4*)A2l)[t] = lv;
    }
  }
}

// ---------- split-bf16 MFMA GEMM, 2-phase pipelined, 8-WAVE (512 threads) ----------
// BM=128 BN=128 BK=32, 8 waves (2x4), wave tile 64x32 = 4x2 fragments of 16x16.
// Same LDS layout/tiles/kt order/3-sweep accumulation as the 4-wave version ->
// bit-identical results; only wave->fragment ownership changes. 4 waves/SIMD
// (vs 2) doubles latency hiding across the per-K-step vmcnt(0)+barrier drain.
template<bool RELU>
__global__ __launch_bounds__(512, 4) void gemm_mfma(const unsigned short* __restrict__ Ah,
    const unsigned short* __restrict__ Al, const unsigned short* __restrict__ Bh,
    const unsigned short* __restrict__ Bl, const float* __restrict__ bias,
    float* __restrict__ C) {
  __shared__ char smem[65536];   // 2 buffers x (Ahi 8K | Alo 8K | Bhi 8K | Blo 8K)
  const int tid = threadIdx.x;
  const int l = tid & 63;
  const int w = tid >> 6;        // 0..7
  const int wm = w >> 2;         // 0..1  (row half)
  const int wn = w & 3;          // 0..3  (col quarter)
  const int mblk = blockIdx.y, nblk = blockIdx.x;

  // per-lane global byte addrs of fragment (frag = w, kt = 0); kt step adds 1024B
  const char* gAh = (const char*)Ah + (((size_t)(mblk * 8 + w) * 16) * 64 + l) * 16;
  const char* gAl = (const char*)Al + (((size_t)(mblk * 8 + w) * 16) * 64 + l) * 16;
  const char* gBh = (const char*)Bh + (((size_t)(nblk * 8 + w) * 16) * 64 + l) * 16;
  const char* gBl = (const char*)Bl + (((size_t)(nblk * 8 + w) * 16) * 64 + l) * 16;

  f32x4 acc[4][2];
#pragma unroll
  for (int i = 0; i < 4; ++i)
#pragma unroll
    for (int j = 0; j < 2; ++j) acc[i][j] = (f32x4){0.f, 0.f, 0.f, 0.f};

  auto stage = [&](int buf, int kt) {
    char* base = smem + buf * 32768;
    const size_t ko = (size_t)kt * 1024;
    gload16(gAh + ko, base + w * 1024);            // wave w owns frag w of each array
    gload16(gAl + ko, base + 8192 + w * 1024);
    gload16(gBh + ko, base + 16384 + w * 1024);
    gload16(gBl + ko, base + 24576 + w * 1024);
  };

  auto compute = [&](int buf) {
    const char* base = smem + buf * 32768;
    const short8* sAh = (const short8*)(base);
    const short8* sAl = (const short8*)(base + 8192);
    const short8* sBh = (const short8*)(base + 16384);
    const short8* sBl = (const short8*)(base + 24576);
    short8 a_h[4], a_l[4], b_h[2], b_l[2];
#pragma unroll
    for (int i = 0; i < 4; ++i) {
      a_h[i] = sAh[(wm * 4 + i) * 64 + l];
      a_l[i] = sAl[(wm * 4 + i) * 64 + l];
    }
#pragma unroll
    for (int j = 0; j < 2; ++j) {
      b_h[j] = sBh[(wn * 2 + j) * 64 + l];
      b_l[j] = sBl[(wn * 2 + j) * 64 + l];
    }
    // sweep 1: hi*hi (same-dst MFMAs spaced 8 apart)
#pragma unroll
    for (int i = 0; i < 4; ++i)
#pragma unroll
      for (int j = 0; j < 2; ++j)
        acc[i][j] = __builtin_amdgcn_mfma_f32_16x16x32_bf16(a_h[i], b_h[j], acc[i][j], 0, 0, 0);
    // sweep 2: hi*lo
#pragma unroll
    for (int i = 0; i < 4; ++i)
#pragma unroll
      for (int j = 0; j < 2; ++j)
        acc[i][j] = __builtin_amdgcn_mfma_f32_16x16x32_bf16(a_h[i], b_l[j], acc[i][j], 0, 0, 0);
    // sweep 3: lo*hi
#pragma unroll
    for (int i = 0; i < 4; ++i)
#pragma unroll
      for (int j = 0; j < 2; ++j)
        acc[i][j] = __builtin_amdgcn_mfma_f32_16x16x32_bf16(a_l[i], b_h[j], acc[i][j], 0, 0, 0);
  };

  stage(0, 0);
  __syncthreads();
  int cur = 0;
#pragma unroll 1
  for (int kt = 1; kt < 16; ++kt) {
    stage(cur ^ 1, kt);
    compute(cur);
    __syncthreads();
    cur ^= 1;
  }
  compute(cur);

  // epilogue: D col = lane&15, row = (lane>>4)*4 + r
  const int colb = nblk * 128 + wn * 32 + (l & 15);
  const int rowb = mblk * 128 + wm * 64 + ((l >> 4) << 2);
#pragma unroll
  for (int j = 0; j < 2; ++j) {
    float bv = bias[colb + j * 16];
#pragma unroll
    for (int i = 0; i < 4; ++i) {
#pragma unroll
      for (int r = 0; r < 4; ++r) {
        float v = acc[i][j][r] + bv;
        if (RELU) v = fmaxf(v, 0.f);
        C[(size_t)(rowb + i * 16 + r) * 512 + colb + j * 16] = v;
      }
    }
  }
}

// ---------- z = LN(h @ W2_in + b2) over C=8; one wave per token ----------
__global__ __launch_bounds__(256) void zln_kernel(const float* __restrict__ h,
    const float* __restrict__ W2, const float* __restrict__ b2,
    const float* __restrict__ g, const float* __restrict__ b,
    float* __restrict__ z) {
  int token = blockIdx.x * 4 + (threadIdx.x >> 6);
  int lane = threadIdx.x & 63;
  const float* hr = h + (size_t)token * E_DIM;
  float acc[C_DIM];
#pragma unroll
  for (int c = 0; c < C_DIM; ++c) acc[c] = 0.f;
  for (int e = lane; e < E_DIM; e += 64) {
    float hv = hr[e];
    const float* w = W2 + e * C_DIM;
#pragma unroll
    for (int c = 0; c < C_DIM; ++c) acc[c] = fmaf(hv, w[c], acc[c]);
  }
#pragma unroll
  for (int c = 0; c < C_DIM; ++c) {
#pragma unroll
    for (int off = 32; off > 0; off >>= 1) acc[c] += __shfl_down(acc[c], off);
  }
  if (lane == 0) {
    float v[C_DIM]; float mu = 0.f;
#pragma unroll
    for (int c = 0; c < C_DIM; ++c) { v[c] = acc[c] + b2[c]; mu += v[c]; }
    mu *= 0.125f;
    float var = 0.f;
#pragma unroll
    for (int c = 0; c < C_DIM; ++c) { float d = v[c] - mu; var += d * d; }
    var *= 0.125f;
    float inv = 1.0f / sqrtf(var + LN_EPS);
#pragma unroll
    for (int c = 0; c < C_DIM; ++c)
      z[(size_t)token * C_DIM + c] = ((v[c] - mu) * inv) * g[c] + b[c];
  }
}

// ---------- partial argmin: lane=token, code index uniform (scalar loads) ----------
__global__ __launch_bounds__(256) void vq_partial(const float* __restrict__ z,
    const float* __restrict__ emb, const float* __restrict__ ne,
    float* __restrict__ pbest, int* __restrict__ pidx) {
  int chunk = blockIdx.x & 7;                 // 8 chunks of 1024 codes
  int token = (blockIdx.x >> 3) * 256 + threadIdx.x;
  float zv[C_DIM];
#pragma unroll
  for (int c = 0; c < C_DIM; ++c) zv[c] = z[(size_t)token * C_DIM + c];
  float s = 0.f;
#pragma unroll
  for (int c = 0; c < C_DIM; ++c) s = fmaf(zv[c], zv[c], s);
  float best = 3.402823466e38f; int bi = 0;
  int j0 = chunk * 1024;
  for (int j = j0; j < j0 + 1024; ++j) {
    const float* e = emb + (size_t)j * C_DIM;  // uniform address -> s_load
    float p = 0.f;
#pragma unroll
    for (int c = 0; c < C_DIM; ++c) p = fmaf(zv[c], e[c], p);
    float d = fmaf(-2.f, p, s) + ne[j];
    if (d < best) { best = d; bi = j; }        // strict < : first-occurrence argmin
  }
  pbest[chunk * N_TOK + token] = best;
  pidx[chunk * N_TOK + token] = bi;
}

// ---------- fused combine + gather + LayerNorm (+ idxf) ----------
__global__ __launch_bounds__(128) void gather_ln(const float* __restrict__ oc,
    const float* __restrict__ pbest, const int* __restrict__ pidx,
    const float* __restrict__ gw, const float* __restrict__ bw,
    float* __restrict__ q, float* __restrict__ idxf) {
  int n = blockIdx.x;
  int tid = threadIdx.x;
  // combine 8 chunk-partials (uniform scalar loads; ascending chunk keeps first-occ.)
  float best = pbest[n]; int k = pidx[n];
#pragma unroll
  for (int c = 1; c < 8; ++c) {
    float bb = pbest[c * N_TOK + n]; int i2 = pidx[c * N_TOK + n];
    if (bb < best) { best = bb; k = i2; }
  }
  const float* r = oc + (size_t)k * E_DIM;
  float4 v = ((const float4*)r)[tid];
  __shared__ float red[4];
  int lane = tid & 63, wid = tid >> 6;
  float sum = v.x + v.y + v.z + v.w;
#pragma unroll
  for (int off = 32; off > 0; off >>= 1) sum += __shfl_xor(sum, off);
  if (lane == 0) red[wid] = sum;
  __syncthreads();
  float mu = (red[0] + red[1]) * (1.0f / 512.0f);
  float4 d;
  d.x = v.x - mu; d.y = v.y - mu; d.z = v.z - mu; d.w = v.w - mu;
  float sq = d.x * d.x + d.y * d.y + d.z * d.z + d.w * d.w;
#pragma unroll
  for (int off = 32; off > 0; off >>= 1) sq += __shfl_xor(sq, off);
  if (lane == 0) red[2 + wid] = sq;
  __syncthreads();
  float var = (red[2] + red[3]) * (1.0f / 512.0f);
  float inv = 1.0f / sqrtf(var + LN_EPS);
  float4 gg = ((const float4*)gw)[tid];
  float4 bb = ((const float4*)bw)[tid];
  float4 o;
  o.x = d.x * inv * gg.x + bb.x;
  o.y = d.y * inv * gg.y + bb.y;
  o.z = d.z * inv * gg.z + bb.z;
  o.w = d.w * inv * gg.w + bb.w;
  ((float4*)(q + (size_t)n * E_DIM))[tid] = o;
  if (tid == 0) idxf[n] = (float)k;
}

// ---------- zero the encodings row and plant the 1.0, coalesced (dedicated fill) ----------
__global__ __launch_bounds__(256) void zero_scatter(const float* __restrict__ idxf,
    float* __restrict__ enc) {
  int n = blockIdx.x;
  int tid = threadIdx.x;
  int k = (int)idxf[n];                         // idxf lives OUTSIDE enc region
  float* row = enc + (size_t)n * K_CODES;       // 8192 floats = 2048 float4
  float4 zv = {0.f, 0.f, 0.f, 0.f};
#pragma unroll
  for (int u = 0; u < 8; ++u)
    ((float4*)row)[u * 256 + tid] = zv;
  // float4 (k>>2) was zeroed by thread ((k>>2)&255); same-thread ordered overwrite.
  if (((k >> 2) & 255) == tid) row[k] = 1.0f;
}

extern "C" void kernel_launch(void* const* d_in, const int* in_sizes, int n_in,
                              void* d_out, int out_size, void* d_ws, size_t ws_size,
                              hipStream_t stream) {
  const float* features = (const float*)d_in[0];
  const float* W1_in  = (const float*)d_in[1];
  const float* b1_in  = (const float*)d_in[2];
  const float* W2_in  = (const float*)d_in[3];
  const float* b2_in  = (const float*)d_in[4];
  const float* ln_in_g = (const float*)d_in[5];
  const float* ln_in_b = (const float*)d_in[6];
  const float* emb    = (const float*)d_in[7];
  const float* W1_out = (const float*)d_in[8];
  const float* b1_out = (const float*)d_in[9];
  const float* W2_out = (const float*)d_in[10];
  const float* b2_out = (const float*)d_in[11];
  const float* ln_out_g = (const float*)d_in[12];
  const float* ln_out_b = (const float*)d_in[13];

  float* q    = (float*)d_out;                       // N*E
  float* idxf = q + (size_t)N_TOK * E_DIM;           // N (as float)
  float* enc  = idxf + N_TOK;                        // N*K one-hot

  // Scratch in d_ws when available, else inside enc; either way zero_scatter
  // (dedicated fill-rate kernel) rebuilds enc last. idxf is outside enc.
  const size_t WS_NEED = 26091520ULL * 4ULL;   // 104.4 MB
  const bool use_ws = (d_ws != nullptr) && (ws_size >= WS_NEED);

  float *h, *g, *z, *ne, *pbest; int* pidx;
  unsigned short *A1h, *A1l, *A2h, *A2l, *B1h, *B1l, *B2h, *B2l;
  if (use_ws) {
    float* ws = (float*)d_ws;
    h     = ws;                                // 16384*512
    g     = ws + 8388608;                      // 8192*512
    z     = ws + 12582912;                     // 16384*8
    ne    = ws + 12713984;                     // 8192
    pbest = ws + 12722176;                     // 8*16384
    pidx  = (int*)(ws + 12853248);             // 8*16384
    A1h = (unsigned short*)(ws + 12984320);    // 16384*512 bf16
    A1l = (unsigned short*)(ws + 17178624);
    A2h = (unsigned short*)(ws + 21372928);    // 8192*512 bf16
    A2l = (unsigned short*)(ws + 23470080);
    B1h = (unsigned short*)(ws + 25567232);    // 512*512 bf16
    B1l = (unsigned short*)(ws + 25698304);
    B2h = (unsigned short*)(ws + 25829376);
    B2l = (unsigned short*)(ws + 25960448);    // ends at 26091520
  } else {
    h     = enc;
    g     = enc + 12582912;
    z     = enc + 16777216;
    ne    = enc + 16908288;
    pbest = enc + 16916480;
    pidx  = (int*)(enc + 17063936);
    A1h = (unsigned short*)(enc + 17195008);
    A1l = (unsigned short*)(enc + 21389312);
    A2h = (unsigned short*)(enc + 25583616);
    A2l = (unsigned short*)(enc + 27680768);
    B1h = (unsigned short*)(enc + 29777920);
    B1l = (unsigned short*)(enc + 29908992);
    B2h = (unsigned short*)(enc + 30040064);
    B2l = (unsigned short*)(enc + 30171136);
  }

  // 1. fused prep (all input-only work)
  prep<<<4896, 256, 0, stream>>>(features, W1_in, W2_out, emb, W1_out, b1_out,
                                 A1h, A1l, B1h, B1l, B2h, B2l, A2h, A2l, ne);

  // 2. project_in: h = relu(features @ W1_in + b1)  [8-wave GEMM]
  dim3 g1(4, N_TOK / 128);
  gemm_mfma<true><<<g1, 512, 0, stream>>>(A1h, A1l, B1h, B1l, b1_in, h);

  // 3. z = LN(h @ W2_in + b2)
  zln_kernel<<<N_TOK / 4, 256, 0, stream>>>(h, W2_in, b2_in, ln_in_g, ln_in_b, z);

  // 4. VQ partial argmin
  vq_partial<<<(N_TOK / 256) * 8, 256, 0, stream>>>(z, emb, ne, pbest, pidx);

  // 5. project_out GEMM over codebook  [8-wave GEMM]
  dim3 g2(4, K_CODES / 128);
  gemm_mfma<false><<<g2, 512, 0, stream>>>(A2h, A2l, B2h, B2l, b2_out, g);

  // 6. combine + q[n] = LN(g[idx[n]]) + idxf
  gather_ln<<<N_TOK, 128, 0, stream>>>(g, pbest, pidx, ln_out_g, ln_out_b, q, idxf);

  // 7. encodings: dedicated fill-rate zero + one-hot plant
  zero_scatter<<<N_TOK, 256, 0, stream>>>(idxf, enc);
}